// Round 1
// baseline (985.990 us; speedup 1.0000x reference)
//
#include <hip/hip_runtime.h>

typedef unsigned short u16;
typedef unsigned int u32;
typedef __attribute__((ext_vector_type(4))) float f32x4;
typedef __attribute__((ext_vector_type(8))) short bf16x8;

#define TOK 32768      // B*N tokens
#define KP  832        // padded 784 (13*64) K-dim
#define DHP 448        // padded 392 (7*64)
#define DHPV 512       // padded 392 rows for V^T as B-matrix (4*128)

static __device__ __forceinline__ float bf2f(u16 u){ u32 v = ((u32)u)<<16; return __builtin_bit_cast(float, v); }
static __device__ __forceinline__ u16 f2bf(float f){
  u32 x = __builtin_bit_cast(u32, f);
  u32 r = (x + 0x7fffu + ((x>>16)&1u)) >> 16;   // RNE
  return (u16)r;
}
static __device__ __forceinline__ void gload16(const void* g, void* l){
  __builtin_amdgcn_global_load_lds((const __attribute__((address_space(1))) void*)g,
                                   (__attribute__((address_space(3))) void*)l, 16, 0, 0);
}
static __device__ __forceinline__ float wave_red_sum(float v){
  #pragma unroll
  for (int o = 32; o > 0; o >>= 1) v += __shfl_xor(v, o, 64);
  return v;
}

// ---------------- weight fp32 -> bf16 with zero padding to [*, KP] ----------------
__global__ __launch_bounds__(256) void wconv_k(const float* __restrict__ src, u16* __restrict__ dst,
                                               int srcR, long long total){
  long long i = (long long)blockIdx.x*256 + threadIdx.x;
  if (i >= total) return;
  int r = (int)(i / KP), c = (int)(i % KP);
  float v = (r < srcR && c < 784) ? src[(long long)r*784 + c] : 0.f;
  dst[i] = f2bf(v);
}

// ---------------- zero V^T pad rows (d in [392,512) per bh) ----------------
__global__ __launch_bounds__(256) void vtpad_k(u16* __restrict__ Vt){
  long long i = (long long)blockIdx.x*256 + threadIdx.x;
  const long long total = 64LL*120*1024;
  if (i >= total) return;
  long long bh = i / (120*1024);
  long long r  = ((i >> 10) % 120) + 392;
  long long col = i & 1023;
  Vt[(bh*DHPV + r)*1024 + col] = 0;
}

// ---------------- LayerNorm(x fp32) -> bf16 padded [TOK, KP] ----------------
__global__ __launch_bounds__(256) void ln1_k(const float* __restrict__ x, const float* __restrict__ w,
                                             const float* __restrict__ b, u16* __restrict__ out){
  const int tid = threadIdx.x;
  const long long row = blockIdx.x;
  const float* xr = x + row*784;
  float v[4]; float s = 0.f, ss = 0.f;
  #pragma unroll
  for (int i = 0; i < 4; i++){ int c = tid + i*256; float t = (c < 784) ? xr[c] : 0.f; v[i] = t; s += t; ss += t*t; }
  __shared__ float red[8];
  s = wave_red_sum(s); ss = wave_red_sum(ss);
  if ((tid & 63) == 0){ red[tid>>6] = s; red[4 + (tid>>6)] = ss; }
  __syncthreads();
  float S  = red[0]+red[1]+red[2]+red[3];
  float SS = red[4]+red[5]+red[6]+red[7];
  float mean = S * (1.f/784.f);
  float var  = SS * (1.f/784.f) - mean*mean;
  float rstd = rsqrtf(var + 1e-5f);
  u16* orow = out + row*KP;
  #pragma unroll
  for (int i = 0; i < 4; i++){
    int c = tid + i*256;
    if (c < KP){
      u16 o = 0;
      if (c < 784) o = f2bf((v[i]-mean)*rstd*w[c] + b[c]);
      orow[c] = o;
    }
  }
}

// ---------------- LayerNorm(attnout bf16) + hardswish -> bf16 padded [TOK, KP] ----------------
__global__ __launch_bounds__(256) void ln2hs_k(const u16* __restrict__ a, const float* __restrict__ w,
                                               const float* __restrict__ b, u16* __restrict__ out){
  const int tid = threadIdx.x;
  const long long row = blockIdx.x;
  const u16* ar = a + row*784;
  float v[4]; float s = 0.f, ss = 0.f;
  #pragma unroll
  for (int i = 0; i < 4; i++){ int c = tid + i*256; float t = (c < 784) ? bf2f(ar[c]) : 0.f; v[i] = t; s += t; ss += t*t; }
  __shared__ float red[8];
  s = wave_red_sum(s); ss = wave_red_sum(ss);
  if ((tid & 63) == 0){ red[tid>>6] = s; red[4 + (tid>>6)] = ss; }
  __syncthreads();
  float S  = red[0]+red[1]+red[2]+red[3];
  float SS = red[4]+red[5]+red[6]+red[7];
  float mean = S * (1.f/784.f);
  float var  = SS * (1.f/784.f) - mean*mean;
  float rstd = rsqrtf(var + 1e-5f);
  u16* orow = out + row*KP;
  #pragma unroll
  for (int i = 0; i < 4; i++){
    int c = tid + i*256;
    if (c < KP){
      u16 o = 0;
      if (c < 784){
        float y = (v[i]-mean)*rstd*w[c] + b[c];
        y = y * fminf(fmaxf(y + 3.f, 0.f), 6.f) * (1.f/6.f);   // hardswish
        o = f2bf(y);
      }
      orow[c] = o;
    }
  }
}

// ---------------- in-place L2-normalize Q (x sqrt(scale)) and K rows, zero pads ----------------
__global__ __launch_bounds__(256) void l2n_k(u16* __restrict__ Q, u16* __restrict__ Kb,
                                             const float* __restrict__ scale){
  const int lane = threadIdx.x & 63, wv = threadIdx.x >> 6;
  const long long rid = (long long)blockIdx.x*4 + wv;     // 131072 rows: Q then K
  const bool isK = rid >= 65536;
  const long long idx = isK ? rid - 65536 : rid;
  u16* base = (isK ? Kb : Q) + idx*DHP;
  // 112 chunks of 4 bf16 (8B); chunks 0..97 are real (d<392)
  uint2 t0 = *(const uint2*)(base + lane*4);
  int ch1 = lane + 64;
  uint2 t1 = (ch1 < 112) ? *(const uint2*)(base + ch1*4) : make_uint2(0u,0u);
  float f0[4], f1[4];
  u32 c0[2] = {t0.x, t0.y}, c1[2] = {t1.x, t1.y};
  #pragma unroll
  for (int j = 0; j < 4; j++){
    f0[j] = bf2f((u16)(c0[j>>1] >> ((j&1)*16)));
    f1[j] = bf2f((u16)(c1[j>>1] >> ((j&1)*16)));
  }
  float ssq = 0.f;
  #pragma unroll
  for (int j = 0; j < 4; j++) ssq += f0[j]*f0[j];
  if (ch1 < 98){
    #pragma unroll
    for (int j = 0; j < 4; j++) ssq += f1[j]*f1[j];
  }
  ssq = wave_red_sum(ssq);
  float fac = 1.f / fmaxf(sqrtf(ssq), 1e-12f);
  if (!isK) fac *= sqrtf(scale[(int)((idx >> 10) & 1)]);   // fold sqrt(scale[h]) into q
  u32 o0[2], o1[2];
  #pragma unroll
  for (int j = 0; j < 2; j++){
    u16 lo = f2bf(f0[2*j]*fac),   hi = f2bf(f0[2*j+1]*fac);
    o0[j] = (u32)lo | ((u32)hi << 16);
    u16 lo1 = (ch1 < 98) ? f2bf(f1[2*j]*fac)   : (u16)0;
    u16 hi1 = (ch1 < 98) ? f2bf(f1[2*j+1]*fac) : (u16)0;
    o1[j] = (u32)lo1 | ((u32)hi1 << 16);
  }
  *(uint2*)(base + lane*4) = make_uint2(o0[0], o0[1]);
  if (ch1 < 112) *(uint2*)(base + ch1*4) = make_uint2(o1[0], o1[1]);
}

// ---------------- rowsum of P (bf16 [65536,1024]) -> fp32 ----------------
__global__ __launch_bounds__(256) void rowsum_k(const u16* __restrict__ P, float* __restrict__ rs){
  const int lane = threadIdx.x & 63, wv = threadIdx.x >> 6;
  const long long row = (long long)blockIdx.x*4 + wv;
  const uint4* p4 = (const uint4*)(P + row*1024);
  uint4 a = p4[lane], b = p4[lane + 64];
  u32 w[8] = {a.x,a.y,a.z,a.w,b.x,b.y,b.z,b.w};
  float s = 0.f;
  #pragma unroll
  for (int j = 0; j < 8; j++) s += bf2f((u16)(w[j]&0xffffu)) + bf2f((u16)(w[j]>>16));
  s = wave_red_sum(s);
  if (lane == 0) rs[row] = s;
}

// ---------------- 128x128 bf16 MFMA GEMM: C = A @ B^T, fused epilogues ----------------
// EPI 0: QK proj scatter  1: V^T  2: exp->P  3: PV/rsum->attnout  4: FFN+hardswish+residual  5: final fp32
template<int EPI>
__global__ __launch_bounds__(256) void gemm_k(const u16* __restrict__ Ab, const u16* __restrict__ Bb,
    int lda, int ldb, int nkt, long long sA, long long sB,
    const float* __restrict__ fp0, void* __restrict__ vp1, void* __restrict__ vp2)
{
  __shared__ u16 Al[128*64];
  __shared__ u16 Bl[128*64];
  const int tid = threadIdx.x;
  const int lane = tid & 63;
  const int wv = tid >> 6;
  const int wr = wv >> 1, wc = wv & 1;
  const int z = blockIdx.z;
  const u16* A  = Ab + (long long)z*sA + (long long)blockIdx.y*128*lda;
  const u16* Bp = Bb + (long long)z*sB + (long long)blockIdx.x*128*ldb;

  f32x4 acc[4][4];
  #pragma unroll
  for (int m = 0; m < 4; m++)
    #pragma unroll
    for (int n = 0; n < 4; n++) acc[m][n] = f32x4{0.f,0.f,0.f,0.f};

  for (int kt = 0; kt < nkt; ++kt){
    const int k0 = kt*64;
    #pragma unroll
    for (int i = 0; i < 4; i++){
      int c = i*256 + tid;          // 16B chunk id; row = c/8, k-off = (c%8)*8
      int row = c >> 3;
      int kc = (c & 7) * 8;
      gload16(A  + (long long)row*lda + (k0 + kc), (void*)(Al + i*2048 + wv*512));
      gload16(Bp + (long long)row*ldb + (k0 + kc), (void*)(Bl + i*2048 + wv*512));
    }
    __syncthreads();
    #pragma unroll
    for (int kk = 0; kk < 64; kk += 32){
      bf16x8 a[4], b[4];
      #pragma unroll
      for (int m = 0; m < 4; m++)
        a[m] = *(const bf16x8*)(Al + (wr*64 + m*16 + (lane&15))*64 + kk + (lane>>4)*8);
      #pragma unroll
      for (int n = 0; n < 4; n++)
        b[n] = *(const bf16x8*)(Bl + (wc*64 + n*16 + (lane&15))*64 + kk + (lane>>4)*8);
      #pragma unroll
      for (int m = 0; m < 4; m++)
        #pragma unroll
        for (int n = 0; n < 4; n++)
          acc[m][n] = __builtin_amdgcn_mfma_f32_16x16x32_bf16(a[m], b[n], acc[m][n], 0, 0, 0);
    }
    __syncthreads();
  }

  const int tm = blockIdx.y*128 + wr*64;
  const int tn = blockIdx.x*128 + wc*64;
  #pragma unroll
  for (int m = 0; m < 4; m++){
    #pragma unroll
    for (int n = 0; n < 4; n++){
      #pragma unroll
      for (int i = 0; i < 4; i++){
        const int row = tm + m*16 + (lane>>4)*4 + i;   // C/D layout: col=lane&15, row=(lane>>4)*4+i
        const int col = tn + n*16 + (lane&15);
        float v = acc[m][n][i];
        if constexpr (EPI == 0){            // QKV(QK part): scatter to Qn/Kn [bh][n][DHP]
          if (col < 1568){
            float val = v + fp0[col];
            int within = (col < 784) ? col : col - 784;
            int hh = within / 392;
            int d  = within - hh*392;
            int bb = row >> 10, nn = row & 1023;
            u16* dst = (u16*)((col < 784) ? vp1 : vp2);
            dst[((long long)((bb*2 + hh)*1024 + nn))*DHP + d] = f2bf(val);
          }
        } else if constexpr (EPI == 1){     // V^T: rows = head-dim, cols = tokens
          if (row < 784){
            float val = v + fp0[row];
            int hh = row / 392;
            int d  = row - hh*392;
            int bb = col >> 10, nn = col & 1023;
            ((u16*)vp1)[((long long)((bb*2 + hh)*DHPV + d))*1024 + nn] = f2bf(val);
          }
        } else if constexpr (EPI == 2){     // P = exp(sim)  (|sim|<=0.1, no max needed)
          ((u16*)vp1)[(long long)z*1048576 + (long long)row*1024 + col] = f2bf(__expf(v));
        } else if constexpr (EPI == 3){     // attnout = (P@V)/rowsum, merge heads
          if (col < 392){
            float val = v / fp0[z*1024 + row];
            int bb = z >> 1, hh = z & 1;
            ((u16*)vp1)[((long long)(bb*1024 + row))*784 + hh*392 + col] = f2bf(val);
          }
        } else if constexpr (EPI == 4){     // s = h + hardswish(ffn)
          if (col < KP){
            u16 o = 0;
            if (col < 784){
              float f = v + fp0[col];
              f = f * fminf(fmaxf(f + 3.f, 0.f), 6.f) * (1.f/6.f);
              float hv = bf2f(((const u16*)vp1)[(long long)row*KP + col]);
              o = f2bf(hv + f);
            }
            ((u16*)vp2)[(long long)row*KP + col] = o;
          }
        } else {                            // EPI 5: final fp32 output
          if (col < 784){
            ((float*)vp1)[(long long)row*784 + col] = v + fp0[col];
          }
        }
      }
    }
  }
}

extern "C" void kernel_launch(void* const* d_in, const int* in_sizes, int n_in,
                              void* d_out, int out_size, void* d_ws, size_t ws_size,
                              hipStream_t stream)
{
  const float* x     = (const float*)d_in[0];
  const float* ln_w  = (const float*)d_in[1];
  const float* ln_b  = (const float*)d_in[2];
  const float* qkv_w = (const float*)d_in[3];
  const float* qkv_b = (const float*)d_in[4];
  const float* scale = (const float*)d_in[5];
  const float* out_w = (const float*)d_in[6];
  const float* out_b = (const float*)d_in[7];
  const float* ffn_w = (const float*)d_in[8];
  const float* ffn_b = (const float*)d_in[9];

  char* wsp = (char*)d_ws;
  auto alloc = [&](long long bytes)->char*{ char* p = wsp; wsp += (bytes + 255) & ~255LL; return p; };
  u16* XN  = (u16*)alloc((long long)TOK*KP*2);      // LN1 output (later aliased as attnout)
  u16* WQK = (u16*)alloc(1664LL*KP*2);              // qkv_w rows 0..1567, padded
  u16* WV  = (u16*)alloc(896LL*KP*2);               // qkv_w rows 1568..2351, padded
  u16* WFF = (u16*)alloc(896LL*KP*2);
  u16* WO  = (u16*)alloc(896LL*KP*2);
  u16* QN  = (u16*)alloc(64LL*1024*DHP*2);          // later aliased as h
  u16* KN  = (u16*)alloc(64LL*1024*DHP*2);          // later aliased as s
  u16* VT  = (u16*)alloc(64LL*DHPV*1024*2);
  u16* P   = (u16*)alloc(64LL*1024*1024*2);
  float* RS = (float*)alloc(65536LL*4);
  u16* ATT = XN;   // alias: XN dead after V^T GEMM
  u16* H   = QN;   // alias: QN dead after S GEMM
  u16* S   = KN;   // alias: KN dead after S GEMM
  (void)ws_size; (void)in_sizes; (void)n_in; (void)out_size;

  // weights -> bf16 padded
  wconv_k<<<dim3((1664*KP + 255)/256), 256, 0, stream>>>(qkv_w, WQK, 1568, 1664LL*KP);
  wconv_k<<<dim3((896*KP + 255)/256),  256, 0, stream>>>(qkv_w + 1568LL*784, WV, 784, 896LL*KP);
  wconv_k<<<dim3((896*KP + 255)/256),  256, 0, stream>>>(ffn_w, WFF, 784, 896LL*KP);
  wconv_k<<<dim3((896*KP + 255)/256),  256, 0, stream>>>(out_w, WO,  784, 896LL*KP);
  vtpad_k<<<dim3((64*120*1024 + 255)/256), 256, 0, stream>>>(VT);

  // 1) LN1
  ln1_k<<<dim3(TOK), 256, 0, stream>>>(x, ln_w, ln_b, XN);
  // 2) QK projection: [32768,832] @ [1664,832]^T -> scatter Qn,Kn
  gemm_k<0><<<dim3(13, 256, 1), 256, 0, stream>>>(XN, WQK, KP, KP, 13, 0LL, 0LL, qkv_b, QN, KN);
  // 3) V^T: [896,832] @ [32768,832]^T -> Vt[bh][d][tok]
  gemm_k<1><<<dim3(256, 7, 1), 256, 0, stream>>>(WV, XN, KP, KP, 13, 0LL, 0LL, qkv_b + 1568, VT, nullptr);
  // 4) l2norm q (x sqrt(scale)), k; zero pads
  l2n_k<<<dim3(32768), 256, 0, stream>>>(QN, KN, scale);
  // 5) P = exp(q@k^T) per bh
  gemm_k<2><<<dim3(8, 8, 64), 256, 0, stream>>>(QN, KN, DHP, DHP, 7,
      (long long)1024*DHP, (long long)1024*DHP, nullptr, P, nullptr);
  // 6) rowsum(P)
  rowsum_k<<<dim3(16384), 256, 0, stream>>>(P, RS);
  // 7) attnout = (P @ Vt^T)/rowsum
  gemm_k<3><<<dim3(4, 8, 64), 256, 0, stream>>>(P, VT, 1024, 1024, 16,
      1048576LL, (long long)DHPV*1024, RS, ATT, nullptr);
  // 8) LN2 + hardswish -> h
  ln2hs_k<<<dim3(TOK), 256, 0, stream>>>(ATT, ln_w, ln_b, H);
  // 9) s = h + hardswish(h @ ffn_w^T + ffn_b)
  gemm_k<4><<<dim3(7, 256, 1), 256, 0, stream>>>(H, WFF, KP, KP, 13, 0LL, 0LL, ffn_b, H, S);
  // 10) y = s @ out_w^T + out_b  (fp32 out)
  gemm_k<5><<<dim3(7, 256, 1), 256, 0, stream>>>(S, WO, KP, KP, 13, 0LL, 0LL, out_b, d_out, nullptr);
}

// Round 2
// 954.457 us; speedup vs baseline: 1.0330x; 1.0330x over previous
//
#include <hip/hip_runtime.h>

typedef unsigned short u16;
typedef unsigned int u32;
typedef __attribute__((ext_vector_type(4))) float f32x4;
typedef __attribute__((ext_vector_type(8))) short bf16x8;

#define TOK 32768      // B*N tokens
#define KP  832        // padded 784 (13*64) K-dim
#define DHP 448        // padded 392 (7*64)
#define DHPV 512       // padded 392 rows for V^T as B-matrix (4*128)
#define NQKV 2432      // padded 2352 (19*128) rows of qkv_w

static __device__ __forceinline__ float bf2f(u16 u){ u32 v = ((u32)u)<<16; return __builtin_bit_cast(float, v); }
static __device__ __forceinline__ u16 f2bf(float f){
  u32 x = __builtin_bit_cast(u32, f);
  u32 r = (x + 0x7fffu + ((x>>16)&1u)) >> 16;   // RNE
  return (u16)r;
}
static __device__ __forceinline__ void gload16(const void* g, void* l){
  __builtin_amdgcn_global_load_lds((const __attribute__((address_space(1))) void*)g,
                                   (__attribute__((address_space(3))) void*)l, 16, 0, 0);
}
static __device__ __forceinline__ float wave_red_sum(float v){
  #pragma unroll
  for (int o = 32; o > 0; o >>= 1) v += __shfl_xor(v, o, 64);
  return v;
}

// ---------------- weight fp32 -> bf16 with zero padding to [*, KP] ----------------
__global__ __launch_bounds__(256) void wconv_k(const float* __restrict__ src, u16* __restrict__ dst,
                                               int srcR, long long total){
  long long i = (long long)blockIdx.x*256 + threadIdx.x;
  if (i >= total) return;
  int r = (int)(i / KP), c = (int)(i % KP);
  float v = (r < srcR && c < 784) ? src[(long long)r*784 + c] : 0.f;
  dst[i] = f2bf(v);
}

// ---------------- zero V^T pad rows (d in [392,512) per bh) ----------------
__global__ __launch_bounds__(256) void vtpad_k(u16* __restrict__ Vt){
  long long i = (long long)blockIdx.x*256 + threadIdx.x;
  const long long total = 64LL*120*1024;
  if (i >= total) return;
  long long bh = i / (120*1024);
  long long r  = ((i >> 10) % 120) + 392;
  long long col = i & 1023;
  Vt[(bh*DHPV + r)*1024 + col] = 0;
}

// ---------------- zero rowsum accumulator ----------------
__global__ __launch_bounds__(256) void rszero_k(float* __restrict__ rs){
  rs[blockIdx.x*256 + threadIdx.x] = 0.f;
}

// ---------------- LayerNorm(x fp32) -> bf16 padded [TOK, KP] ----------------
__global__ __launch_bounds__(256) void ln1_k(const float* __restrict__ x, const float* __restrict__ w,
                                             const float* __restrict__ b, u16* __restrict__ out){
  const int tid = threadIdx.x;
  const long long row = blockIdx.x;
  const float* xr = x + row*784;
  float v[4]; float s = 0.f, ss = 0.f;
  #pragma unroll
  for (int i = 0; i < 4; i++){ int c = tid + i*256; float t = (c < 784) ? xr[c] : 0.f; v[i] = t; s += t; ss += t*t; }
  __shared__ float red[8];
  s = wave_red_sum(s); ss = wave_red_sum(ss);
  if ((tid & 63) == 0){ red[tid>>6] = s; red[4 + (tid>>6)] = ss; }
  __syncthreads();
  float S  = red[0]+red[1]+red[2]+red[3];
  float SS = red[4]+red[5]+red[6]+red[7];
  float mean = S * (1.f/784.f);
  float var  = SS * (1.f/784.f) - mean*mean;
  float rstd = rsqrtf(var + 1e-5f);
  u16* orow = out + row*KP;
  #pragma unroll
  for (int i = 0; i < 4; i++){
    int c = tid + i*256;
    if (c < KP){
      u16 o = 0;
      if (c < 784) o = f2bf((v[i]-mean)*rstd*w[c] + b[c]);
      orow[c] = o;
    }
  }
}

// ---------------- LayerNorm(attnout bf16) + hardswish -> bf16 padded [TOK, KP] ----------------
__global__ __launch_bounds__(256) void ln2hs_k(const u16* __restrict__ a, const float* __restrict__ w,
                                               const float* __restrict__ b, u16* __restrict__ out){
  const int tid = threadIdx.x;
  const long long row = blockIdx.x;
  const u16* ar = a + row*784;
  float v[4]; float s = 0.f, ss = 0.f;
  #pragma unroll
  for (int i = 0; i < 4; i++){ int c = tid + i*256; float t = (c < 784) ? bf2f(ar[c]) : 0.f; v[i] = t; s += t; ss += t*t; }
  __shared__ float red[8];
  s = wave_red_sum(s); ss = wave_red_sum(ss);
  if ((tid & 63) == 0){ red[tid>>6] = s; red[4 + (tid>>6)] = ss; }
  __syncthreads();
  float S  = red[0]+red[1]+red[2]+red[3];
  float SS = red[4]+red[5]+red[6]+red[7];
  float mean = S * (1.f/784.f);
  float var  = SS * (1.f/784.f) - mean*mean;
  float rstd = rsqrtf(var + 1e-5f);
  u16* orow = out + row*KP;
  #pragma unroll
  for (int i = 0; i < 4; i++){
    int c = tid + i*256;
    if (c < KP){
      u16 o = 0;
      if (c < 784){
        float y = (v[i]-mean)*rstd*w[c] + b[c];
        y = y * fminf(fmaxf(y + 3.f, 0.f), 6.f) * (1.f/6.f);   // hardswish
        o = f2bf(y);
      }
      orow[c] = o;
    }
  }
}

// ---------------- in-place L2-normalize Q (x sqrt(scale)) and K rows, zero pads ----------------
__global__ __launch_bounds__(256) void l2n_k(u16* __restrict__ Q, u16* __restrict__ Kb,
                                             const float* __restrict__ scale){
  const int lane = threadIdx.x & 63, wv = threadIdx.x >> 6;
  const long long rid = (long long)blockIdx.x*4 + wv;     // 131072 rows: Q then K
  const bool isK = rid >= 65536;
  const long long idx = isK ? rid - 65536 : rid;
  u16* base = (isK ? Kb : Q) + idx*DHP;
  uint2 t0 = *(const uint2*)(base + lane*4);
  int ch1 = lane + 64;
  uint2 t1 = (ch1 < 112) ? *(const uint2*)(base + ch1*4) : make_uint2(0u,0u);
  float f0[4], f1[4];
  u32 c0[2] = {t0.x, t0.y}, c1[2] = {t1.x, t1.y};
  #pragma unroll
  for (int j = 0; j < 4; j++){
    f0[j] = bf2f((u16)(c0[j>>1] >> ((j&1)*16)));
    f1[j] = bf2f((u16)(c1[j>>1] >> ((j&1)*16)));
  }
  float ssq = 0.f;
  #pragma unroll
  for (int j = 0; j < 4; j++) ssq += f0[j]*f0[j];
  if (ch1 < 98){
    #pragma unroll
    for (int j = 0; j < 4; j++) ssq += f1[j]*f1[j];
  }
  ssq = wave_red_sum(ssq);
  float fac = 1.f / fmaxf(sqrtf(ssq), 1e-12f);
  if (!isK) fac *= sqrtf(scale[(int)((idx >> 10) & 1)]);   // fold sqrt(scale[h]) into q
  u32 o0[2], o1[2];
  #pragma unroll
  for (int j = 0; j < 2; j++){
    u16 lo = f2bf(f0[2*j]*fac),   hi = f2bf(f0[2*j+1]*fac);
    o0[j] = (u32)lo | ((u32)hi << 16);
    u16 lo1 = (ch1 < 98) ? f2bf(f1[2*j]*fac)   : (u16)0;
    u16 hi1 = (ch1 < 98) ? f2bf(f1[2*j+1]*fac) : (u16)0;
    o1[j] = (u32)lo1 | ((u32)hi1 << 16);
  }
  *(uint2*)(base + lane*4) = make_uint2(o0[0], o0[1]);
  if (ch1 < 112) *(uint2*)(base + ch1*4) = make_uint2(o1[0], o1[1]);
}

// ---------------- 128x128 bf16 MFMA GEMM: C = A @ B^T, fused epilogues ----------------
// EPI 0: flipped QKV -> scatter Q,K (packed 8B) + V^T    2: exp->P + fused rowsum atomics
// EPI 3: PV/rsum->attnout   4: FFN+hardswish+residual    5: final fp32
// ORDER: 0 = x-fastest linearization, 1 = y-fastest (fast axis = small operand's dim)
template<int EPI, int ORDER>
__global__ __launch_bounds__(256) void gemm_k(const u16* __restrict__ Ab, const u16* __restrict__ Bb,
    int lda, int ldb, int nkt, long long sA, long long sB,
    const float* __restrict__ fp0, void* __restrict__ vp1, void* __restrict__ vp2, void* __restrict__ vp3)
{
  __shared__ u16 Al[128*64];
  __shared__ u16 Bl[128*64];
  const int tid = threadIdx.x;
  const int lane = tid & 63;
  const int wv = tid >> 6;
  const int wr = wv >> 1, wc = wv & 1;

  // ---- T1: bijective XCD-aware block swizzle (m204) ----
  const int gx = gridDim.x, gy = gridDim.y;
  const int nwg = gx*gy*(int)gridDim.z;
  int lin = (ORDER == 0) ? ((int)blockIdx.x + gx*((int)blockIdx.y + gy*(int)blockIdx.z))
                         : ((int)blockIdx.y + gy*((int)blockIdx.x + gx*(int)blockIdx.z));
  const int q8 = nwg >> 3, r8 = nwg & 7;
  const int xcd = lin & 7, base8 = lin >> 3;
  int wg = (xcd < r8 ? xcd*(q8+1) : r8*(q8+1) + (xcd-r8)*q8) + base8;
  int bx, by, bz;
  if (ORDER == 0){ bx = wg % gx; wg /= gx; by = wg % gy; bz = wg / gy; }
  else           { by = wg % gy; wg /= gy; bx = wg % gx; bz = wg / gx; }

  const u16* A  = Ab + (long long)bz*sA + (long long)by*128*lda;
  const u16* Bp = Bb + (long long)bz*sB + (long long)bx*128*ldb;

  f32x4 acc[4][4];
  #pragma unroll
  for (int m = 0; m < 4; m++)
    #pragma unroll
    for (int n = 0; n < 4; n++) acc[m][n] = f32x4{0.f,0.f,0.f,0.f};

  for (int kt = 0; kt < nkt; ++kt){
    const int k0 = kt*64;
    #pragma unroll
    for (int i = 0; i < 4; i++){
      int c = i*256 + tid;          // 16B chunk id; row = c/8, k-off = (c%8)*8
      int row = c >> 3;
      int kc = (c & 7) * 8;
      gload16(A  + (long long)row*lda + (k0 + kc), (void*)(Al + i*2048 + wv*512));
      gload16(Bp + (long long)row*ldb + (k0 + kc), (void*)(Bl + i*2048 + wv*512));
    }
    __syncthreads();
    #pragma unroll
    for (int kk = 0; kk < 64; kk += 32){
      bf16x8 a[4], b[4];
      #pragma unroll
      for (int m = 0; m < 4; m++)
        a[m] = *(const bf16x8*)(Al + (wr*64 + m*16 + (lane&15))*64 + kk + (lane>>4)*8);
      #pragma unroll
      for (int n = 0; n < 4; n++)
        b[n] = *(const bf16x8*)(Bl + (wc*64 + n*16 + (lane&15))*64 + kk + (lane>>4)*8);
      #pragma unroll
      for (int m = 0; m < 4; m++)
        #pragma unroll
        for (int n = 0; n < 4; n++)
          acc[m][n] = __builtin_amdgcn_mfma_f32_16x16x32_bf16(a[m], b[n], acc[m][n], 0, 0, 0);
    }
    __syncthreads();
  }

  const int tm = by*128 + wr*64;
  const int tn = bx*128 + wc*64;

  if constexpr (EPI == 0){
    // C = qkv_w @ xn^T : rows = qkv output dim (2432 padded), cols = tokens.
    // Q/K: packed ushort4 along d (4-aligned, segment boundaries at 392k are 4-aligned).
    // V: transposed scatter into VT[bh][d][tok].
    u16* Qn = (u16*)vp1; u16* Kn = (u16*)vp2; u16* Vt = (u16*)vp3;
    #pragma unroll
    for (int m = 0; m < 4; m++){
      const int row0 = tm + m*16 + (lane>>4)*4;     // d_full base (4-aligned)
      if (row0 < 2352){
        const int seg = row0 / 392;                 // 0,1=Q(h0,h1) 2,3=K 4,5=V
        const int hh = seg & 1;
        const int dd0 = row0 - seg*392;
        const float b0 = fp0[row0], b1 = fp0[row0+1], b2 = fp0[row0+2], b3 = fp0[row0+3];
        #pragma unroll
        for (int n = 0; n < 4; n++){
          const int col = tn + n*16 + (lane&15);    // token id
          const int bb = col >> 10, nn = col & 1023;
          const long long bhrow = (long long)((bb*2 + hh)*1024 + nn);
          if (seg < 4){
            u16* dst = (seg < 2) ? Qn : Kn;
            ushort4 pk;
            pk.x = f2bf(acc[m][n][0] + b0);
            pk.y = f2bf(acc[m][n][1] + b1);
            pk.z = f2bf(acc[m][n][2] + b2);
            pk.w = f2bf(acc[m][n][3] + b3);
            *(ushort4*)(dst + bhrow*DHP + dd0) = pk;
          } else {
            const long long vb = ((long long)(bb*2 + hh)*DHPV + dd0)*1024 + nn;
            Vt[vb        ] = f2bf(acc[m][n][0] + b0);
            Vt[vb + 1024 ] = f2bf(acc[m][n][1] + b1);
            Vt[vb + 2048 ] = f2bf(acc[m][n][2] + b2);
            Vt[vb + 3072 ] = f2bf(acc[m][n][3] + b3);
          }
        }
      }
    }
  } else if constexpr (EPI == 2){
    // P = exp(sim) (|sim|<=~0.1, no max needed) + fused rowsum (atomic per row per wave)
    u16* Pb = (u16*)vp1; float* rs = (float*)vp2;
    #pragma unroll
    for (int m = 0; m < 4; m++){
      #pragma unroll
      for (int i = 0; i < 4; i++){
        const int row = tm + m*16 + (lane>>4)*4 + i;
        float s = 0.f;
        #pragma unroll
        for (int n = 0; n < 4; n++){
          const int col = tn + n*16 + (lane&15);
          u16 pb = f2bf(__expf(acc[m][n][i]));
          Pb[(long long)bz*1048576 + (long long)row*1024 + col] = pb;
          s += bf2f(pb);
        }
        s += __shfl_xor(s, 1, 64); s += __shfl_xor(s, 2, 64);
        s += __shfl_xor(s, 4, 64); s += __shfl_xor(s, 8, 64);
        if ((lane & 15) == 0) atomicAdd(rs + bz*1024 + row, s);
      }
    }
  } else {
    #pragma unroll
    for (int m = 0; m < 4; m++){
      #pragma unroll
      for (int n = 0; n < 4; n++){
        #pragma unroll
        for (int i = 0; i < 4; i++){
          const int row = tm + m*16 + (lane>>4)*4 + i;
          const int col = tn + n*16 + (lane&15);
          float v = acc[m][n][i];
          if constexpr (EPI == 3){            // attnout = (P@V)/rowsum, merge heads
            if (col < 392){
              float val = v / fp0[bz*1024 + row];
              int bb = bz >> 1, hh = bz & 1;
              ((u16*)vp1)[((long long)(bb*1024 + row))*784 + hh*392 + col] = f2bf(val);
            }
          } else if constexpr (EPI == 4){     // s = h + hardswish(ffn)
            if (col < KP){
              u16 o = 0;
              if (col < 784){
                float f = v + fp0[col];
                f = f * fminf(fmaxf(f + 3.f, 0.f), 6.f) * (1.f/6.f);
                float hv = bf2f(((const u16*)vp1)[(long long)row*KP + col]);
                o = f2bf(hv + f);
              }
              ((u16*)vp2)[(long long)row*KP + col] = o;
            }
          } else {                            // EPI 5: final fp32 output
            if (col < 784){
              ((float*)vp1)[(long long)row*784 + col] = v + fp0[col];
            }
          }
        }
      }
    }
  }
}

extern "C" void kernel_launch(void* const* d_in, const int* in_sizes, int n_in,
                              void* d_out, int out_size, void* d_ws, size_t ws_size,
                              hipStream_t stream)
{
  const float* x     = (const float*)d_in[0];
  const float* ln_w  = (const float*)d_in[1];
  const float* ln_b  = (const float*)d_in[2];
  const float* qkv_w = (const float*)d_in[3];
  const float* qkv_b = (const float*)d_in[4];
  const float* scale = (const float*)d_in[5];
  const float* out_w = (const float*)d_in[6];
  const float* out_b = (const float*)d_in[7];
  const float* ffn_w = (const float*)d_in[8];
  const float* ffn_b = (const float*)d_in[9];

  char* wsp = (char*)d_ws;
  auto alloc = [&](long long bytes)->char*{ char* p = wsp; wsp += (bytes + 255) & ~255LL; return p; };
  u16* XN   = (u16*)alloc((long long)TOK*KP*2);     // LN1 output (later aliased as attnout)
  u16* WQKV = (u16*)alloc((long long)NQKV*KP*2);    // qkv_w padded [2432, 832]
  u16* WFF  = (u16*)alloc(896LL*KP*2);
  u16* WO   = (u16*)alloc(896LL*KP*2);
  u16* QN   = (u16*)alloc(64LL*1024*DHP*2);         // later aliased as h
  u16* KN   = (u16*)alloc(64LL*1024*DHP*2);         // later aliased as s
  u16* VT   = (u16*)alloc(64LL*DHPV*1024*2);
  u16* P    = (u16*)alloc(64LL*1024*1024*2);
  float* RS = (float*)alloc(65536LL*4);
  u16* ATT = XN;   // alias: XN dead after QKV GEMM
  u16* H   = QN;   // alias: QN dead after P GEMM
  u16* S   = KN;   // alias: KN dead after P GEMM
  (void)ws_size; (void)in_sizes; (void)n_in; (void)out_size;

  // weights -> bf16 padded
  wconv_k<<<dim3((NQKV*KP + 255)/256), 256, 0, stream>>>(qkv_w, WQKV, 2352, (long long)NQKV*KP);
  wconv_k<<<dim3((896*KP + 255)/256),  256, 0, stream>>>(ffn_w, WFF, 784, 896LL*KP);
  wconv_k<<<dim3((896*KP + 255)/256),  256, 0, stream>>>(out_w, WO,  784, 896LL*KP);
  vtpad_k<<<dim3((64*120*1024 + 255)/256), 256, 0, stream>>>(VT);
  rszero_k<<<dim3(256), 256, 0, stream>>>(RS);

  // 1) LN1
  ln1_k<<<dim3(TOK), 256, 0, stream>>>(x, ln_w, ln_b, XN);
  // 2) QKV (flipped): [2432,832] @ [32768,832]^T -> scatter Qn,Kn (packed), Vt (transposed)
  //    y = small (weights) dim -> ORDER=1 (y-fastest): weights cycle in L2, tokens fetched once
  gemm_k<0,1><<<dim3(256, 19, 1), 256, 0, stream>>>(WQKV, XN, KP, KP, 13, 0LL, 0LL,
      qkv_b, QN, KN, VT);
  // 3) l2norm q (x sqrt(scale)), k; zero pads
  l2n_k<<<dim3(32768), 256, 0, stream>>>(QN, KN, scale);
  // 4) P = exp(q@k^T) per bh, fused rowsum
  gemm_k<2,0><<<dim3(8, 8, 64), 256, 0, stream>>>(QN, KN, DHP, DHP, 7,
      (long long)1024*DHP, (long long)1024*DHP, nullptr, P, RS, nullptr);
  // 5) attnout = (P @ Vt^T)/rowsum
  gemm_k<3,0><<<dim3(4, 8, 64), 256, 0, stream>>>(P, VT, 1024, 1024, 16,
      1048576LL, (long long)DHPV*1024, RS, ATT, nullptr, nullptr);
  // 6) LN2 + hardswish -> h
  ln2hs_k<<<dim3(TOK), 256, 0, stream>>>(ATT, ln_w, ln_b, H);
  // 7) s = h + hardswish(h @ ffn_w^T + ffn_b)   (x = small weights dim -> ORDER=0)
  gemm_k<4,0><<<dim3(7, 256, 1), 256, 0, stream>>>(H, WFF, KP, KP, 13, 0LL, 0LL, ffn_b, H, S, nullptr);
  // 8) y = s @ out_w^T + out_b  (fp32 out)
  gemm_k<5,0><<<dim3(7, 256, 1), 256, 0, stream>>>(S, WO, KP, KP, 13, 0LL, 0LL, out_b, d_out, nullptr, nullptr);
}

// Round 3
// 865.583 us; speedup vs baseline: 1.1391x; 1.1027x over previous
//
#include <hip/hip_runtime.h>

typedef unsigned short u16;
typedef unsigned int u32;
typedef __attribute__((ext_vector_type(4))) float f32x4;
typedef __attribute__((ext_vector_type(8))) short bf16x8;

#define TOK 32768      // B*N tokens
#define KP  832        // padded 784 (13*64) K-dim
#define DHP 448        // padded 392 (7*64)
#define DHPV 512       // padded 392 rows for V^T as B-matrix
#define NQKV 2560      // padded 2352 (10*256) rows of qkv_w

static __device__ __forceinline__ float bf2f(u16 u){ u32 v = ((u32)u)<<16; return __builtin_bit_cast(float, v); }
static __device__ __forceinline__ u16 f2bf(float f){
  u32 x = __builtin_bit_cast(u32, f);
  u32 r = (x + 0x7fffu + ((x>>16)&1u)) >> 16;   // RNE
  return (u16)r;
}
static __device__ __forceinline__ void gload16(const void* g, void* l){
  __builtin_amdgcn_global_load_lds((const __attribute__((address_space(1))) void*)g,
                                   (__attribute__((address_space(3))) void*)l, 16, 0, 0);
}
static __device__ __forceinline__ float wave_red_sum(float v){
  #pragma unroll
  for (int o = 32; o > 0; o >>= 1) v += __shfl_xor(v, o, 64);
  return v;
}

// ---------------- weight fp32 -> bf16 with zero padding to [*, KP] ----------------
__global__ __launch_bounds__(256) void wconv_k(const float* __restrict__ src, u16* __restrict__ dst,
                                               int srcR, long long total){
  long long i = (long long)blockIdx.x*256 + threadIdx.x;
  if (i >= total) return;
  int r = (int)(i / KP), c = (int)(i % KP);
  float v = (r < srcR && c < 784) ? src[(long long)r*784 + c] : 0.f;
  dst[i] = f2bf(v);
}

// ---------------- zero V^T pad rows (d in [392,512) per bh) ----------------
__global__ __launch_bounds__(256) void vtpad_k(u16* __restrict__ Vt){
  long long i = (long long)blockIdx.x*256 + threadIdx.x;
  const long long total = 64LL*120*1024;
  if (i >= total) return;
  long long bh = i / (120*1024);
  long long r  = ((i >> 10) % 120) + 392;
  long long col = i & 1023;
  Vt[(bh*DHPV + r)*1024 + col] = 0;
}

// ---------------- zero rowsum accumulator ----------------
__global__ __launch_bounds__(256) void rszero_k(float* __restrict__ rs){
  rs[blockIdx.x*256 + threadIdx.x] = 0.f;
}

// ---------------- LayerNorm(x fp32) -> bf16 padded [TOK, KP] ----------------
__global__ __launch_bounds__(256) void ln1_k(const float* __restrict__ x, const float* __restrict__ w,
                                             const float* __restrict__ b, u16* __restrict__ out){
  const int tid = threadIdx.x;
  const long long row = blockIdx.x;
  const float* xr = x + row*784;
  float v[4]; float s = 0.f, ss = 0.f;
  #pragma unroll
  for (int i = 0; i < 4; i++){ int c = tid + i*256; float t = (c < 784) ? xr[c] : 0.f; v[i] = t; s += t; ss += t*t; }
  __shared__ float red[8];
  s = wave_red_sum(s); ss = wave_red_sum(ss);
  if ((tid & 63) == 0){ red[tid>>6] = s; red[4 + (tid>>6)] = ss; }
  __syncthreads();
  float S  = red[0]+red[1]+red[2]+red[3];
  float SS = red[4]+red[5]+red[6]+red[7];
  float mean = S * (1.f/784.f);
  float var  = SS * (1.f/784.f) - mean*mean;
  float rstd = rsqrtf(var + 1e-5f);
  u16* orow = out + row*KP;
  #pragma unroll
  for (int i = 0; i < 4; i++){
    int c = tid + i*256;
    if (c < KP){
      u16 o = 0;
      if (c < 784) o = f2bf((v[i]-mean)*rstd*w[c] + b[c]);
      orow[c] = o;
    }
  }
}

// ---------------- LayerNorm(attnout bf16) + hardswish -> bf16 padded [TOK, KP] ----------------
__global__ __launch_bounds__(256) void ln2hs_k(const u16* __restrict__ a, const float* __restrict__ w,
                                               const float* __restrict__ b, u16* __restrict__ out){
  const int tid = threadIdx.x;
  const long long row = blockIdx.x;
  const u16* ar = a + row*784;
  float v[4]; float s = 0.f, ss = 0.f;
  #pragma unroll
  for (int i = 0; i < 4; i++){ int c = tid + i*256; float t = (c < 784) ? bf2f(ar[c]) : 0.f; v[i] = t; s += t; ss += t*t; }
  __shared__ float red[8];
  s = wave_red_sum(s); ss = wave_red_sum(ss);
  if ((tid & 63) == 0){ red[tid>>6] = s; red[4 + (tid>>6)] = ss; }
  __syncthreads();
  float S  = red[0]+red[1]+red[2]+red[3];
  float SS = red[4]+red[5]+red[6]+red[7];
  float mean = S * (1.f/784.f);
  float var  = SS * (1.f/784.f) - mean*mean;
  float rstd = rsqrtf(var + 1e-5f);
  u16* orow = out + row*KP;
  #pragma unroll
  for (int i = 0; i < 4; i++){
    int c = tid + i*256;
    if (c < KP){
      u16 o = 0;
      if (c < 784){
        float y = (v[i]-mean)*rstd*w[c] + b[c];
        y = y * fminf(fmaxf(y + 3.f, 0.f), 6.f) * (1.f/6.f);   // hardswish
        o = f2bf(y);
      }
      orow[c] = o;
    }
  }
}

// ---------------- in-place L2-normalize Q (x sqrt(scale)) and K rows, zero pads ----------------
__global__ __launch_bounds__(256) void l2n_k(u16* __restrict__ Q, u16* __restrict__ Kb,
                                             const float* __restrict__ scale){
  const int lane = threadIdx.x & 63, wv = threadIdx.x >> 6;
  const long long rid = (long long)blockIdx.x*4 + wv;     // 131072 rows: Q then K
  const bool isK = rid >= 65536;
  const long long idx = isK ? rid - 65536 : rid;
  u16* base = (isK ? Kb : Q) + idx*DHP;
  uint2 t0 = *(const uint2*)(base + lane*4);
  int ch1 = lane + 64;
  uint2 t1 = (ch1 < 112) ? *(const uint2*)(base + ch1*4) : make_uint2(0u,0u);
  float f0[4], f1[4];
  u32 c0[2] = {t0.x, t0.y}, c1[2] = {t1.x, t1.y};
  #pragma unroll
  for (int j = 0; j < 4; j++){
    f0[j] = bf2f((u16)(c0[j>>1] >> ((j&1)*16)));
    f1[j] = bf2f((u16)(c1[j>>1] >> ((j&1)*16)));
  }
  float ssq = 0.f;
  #pragma unroll
  for (int j = 0; j < 4; j++) ssq += f0[j]*f0[j];
  if (ch1 < 98){
    #pragma unroll
    for (int j = 0; j < 4; j++) ssq += f1[j]*f1[j];
  }
  ssq = wave_red_sum(ssq);
  float fac = 1.f / fmaxf(sqrtf(ssq), 1e-12f);
  if (!isK) fac *= sqrtf(scale[(int)((idx >> 10) & 1)]);   // fold sqrt(scale[h]) into q
  u32 o0[2], o1[2];
  #pragma unroll
  for (int j = 0; j < 2; j++){
    u16 lo = f2bf(f0[2*j]*fac),   hi = f2bf(f0[2*j+1]*fac);
    o0[j] = (u32)lo | ((u32)hi << 16);
    u16 lo1 = (ch1 < 98) ? f2bf(f1[2*j]*fac)   : (u16)0;
    u16 hi1 = (ch1 < 98) ? f2bf(f1[2*j+1]*fac) : (u16)0;
    o1[j] = (u32)lo1 | ((u32)hi1 << 16);
  }
  *(uint2*)(base + lane*4) = make_uint2(o0[0], o0[1]);
  if (ch1 < 112) *(uint2*)(base + ch1*4) = make_uint2(o1[0], o1[1]);
}

// =======================================================================================
// 256x256-tile, 8-wave, BK=32, 4-deep ring-buffered MFMA GEMM: C = A @ B^T
// T2 chunk-XOR LDS swizzle + T4 counted vmcnt + T5 setprio. One s_barrier per K-step.
// Ring safety: tile t read from buf[t%4]; tile t+3 staged during t (buf[(t+3)%4] was
// last read at tile t-1, released by the end-of-(t-1) barrier). vmcnt(8) at end of t
// retires exactly tile t+1's 4 loads (FIFO), keeping 8 in flight across the barrier.
// EPI 0: flipped QKV scatter  2: exp->P + rowsum atomics  3: PV/rsum  4: FFN+hs+res  5: fp32 out
// =======================================================================================
template<int EPI, int ORDER>
__global__ __launch_bounds__(512, 2) void gemm8_k(const u16* __restrict__ Ab, const u16* __restrict__ Bb,
    int lda, int ldb, int nkt, long long sA, long long sB,
    const float* __restrict__ fp0, void* __restrict__ vp1, void* __restrict__ vp2, void* __restrict__ vp3)
{
  __shared__ u16 LA[4][8192];   // 4 ring slots x (256 rows x 32 cols) bf16
  __shared__ u16 LB[4][8192];
  const int tid = threadIdx.x;
  const int lane = tid & 63;
  const int wid = tid >> 6;          // 0..7
  const int wr = wid >> 2, wc = wid & 3;

  // ---- T1: bijective XCD-aware block swizzle (m204) ----
  const int gx = gridDim.x, gy = gridDim.y;
  const int nwg = gx*gy*(int)gridDim.z;
  int lin = (ORDER == 0) ? ((int)blockIdx.x + gx*((int)blockIdx.y + gy*(int)blockIdx.z))
                         : ((int)blockIdx.y + gy*((int)blockIdx.x + gx*(int)blockIdx.z));
  const int q8 = nwg >> 3, r8 = nwg & 7;
  const int xcd = lin & 7, base8 = lin >> 3;
  int wg = (xcd < r8 ? xcd*(q8+1) : r8*(q8+1) + (xcd-r8)*q8) + base8;
  int bx, by, bz;
  if (ORDER == 0){ bx = wg % gx; wg /= gx; by = wg % gy; bz = wg / gy; }
  else           { by = wg % gy; wg /= gy; bx = wg % gx; bz = wg / gx; }

  const u16* Abase = Ab + (long long)bz*sA + (long long)by*256*lda;
  const u16* Bbase = Bb + (long long)bz*sB + (long long)bx*256*ldb;

  // staging: thread covers linear LDS 16B-slots s0,s1 per operand. Slot s holds logical
  // col-chunk (s&3)^((row>>1)&3) of row s>>2 -> pre-swizzled GLOBAL source (rule #21).
  const int s0 = tid, s1 = tid + 512;
  const int r0 = s0 >> 2, r1 = s1 >> 2;
  const int kc0 = (((s0 & 3) ^ ((s0 >> 3) & 3)) << 3);
  const int kc1 = (((s1 & 3) ^ ((s1 >> 3) & 3)) << 3);
  const u16* ga0 = Abase + (long long)r0*lda + kc0;
  const u16* ga1 = Abase + (long long)r1*lda + kc1;
  const u16* gb0 = Bbase + (long long)r0*ldb + kc0;
  const u16* gb1 = Bbase + (long long)r1*ldb + kc1;

  // fragment read offsets (u16 units), swizzled: 2-way bank aliasing only
  int offa[8], offb[4];
  #pragma unroll
  for (int m = 0; m < 8; m++){
    int row = wr*128 + m*16 + (lane & 15);
    offa[m] = row*32 + ((((lane >> 4) ^ (row >> 1)) & 3) << 3);
  }
  #pragma unroll
  for (int n = 0; n < 4; n++){
    int row = wc*64 + n*16 + (lane & 15);
    offb[n] = row*32 + ((((lane >> 4) ^ (row >> 1)) & 3) << 3);
  }

  f32x4 acc[8][4];
  #pragma unroll
  for (int m = 0; m < 8; m++)
    #pragma unroll
    for (int n = 0; n < 4; n++) acc[m][n] = f32x4{0.f,0.f,0.f,0.f};

  auto stage = [&](int tt){
    const int b = tt & 3;
    const long long k0 = (long long)(tt << 5);
    gload16(ga0 + k0, (void*)&LA[b][s0*8]);
    gload16(ga1 + k0, (void*)&LA[b][s1*8]);
    gload16(gb0 + k0, (void*)&LB[b][s0*8]);
    gload16(gb1 + k0, (void*)&LB[b][s1*8]);
  };

  // prologue: 3 tiles in flight, retire tile 0 (nkt >= 3 always here)
  stage(0); stage(1); stage(2);
  asm volatile("s_waitcnt vmcnt(8)" ::: "memory");
  __builtin_amdgcn_s_barrier();

  for (int t = 0; t < nkt; ++t){
    if (t + 3 < nkt) stage(t + 3);
    const int b = t & 3;
    bf16x8 af[8], bf[4];
    #pragma unroll
    for (int m = 0; m < 8; m++) af[m] = *(const bf16x8*)&LA[b][offa[m]];
    #pragma unroll
    for (int n = 0; n < 4; n++) bf[n] = *(const bf16x8*)&LB[b][offb[n]];
    __builtin_amdgcn_s_setprio(1);
    #pragma unroll
    for (int m = 0; m < 8; m++)
      #pragma unroll
      for (int n = 0; n < 4; n++)
        acc[m][n] = __builtin_amdgcn_mfma_f32_16x16x32_bf16(af[m], bf[n], acc[m][n], 0, 0, 0);
    __builtin_amdgcn_s_setprio(0);
    if (t + 3 < nkt)      asm volatile("s_waitcnt vmcnt(8)" ::: "memory");
    else if (t + 2 < nkt) asm volatile("s_waitcnt vmcnt(4)" ::: "memory");
    else if (t + 1 < nkt) asm volatile("s_waitcnt vmcnt(0)" ::: "memory");
    if (t + 1 < nkt) __builtin_amdgcn_s_barrier();
  }

  const int tm = by*256 + wr*128;
  const int tn = bx*256 + wc*64;

  if constexpr (EPI == 0){
    // C = qkv_w @ xn^T : rows = qkv dim (2560 padded), cols = tokens.
    u16* Qn = (u16*)vp1; u16* Kn = (u16*)vp2; u16* Vt = (u16*)vp3;
    #pragma unroll
    for (int m = 0; m < 8; m++){
      const int row0 = tm + m*16 + (lane>>4)*4;     // 4-aligned; seg boundaries (392k) 4-aligned
      if (row0 < 2352){
        const int seg = row0 / 392;                 // 0,1=Q(h0,h1) 2,3=K 4,5=V
        const int hh = seg & 1;
        const int dd0 = row0 - seg*392;
        const float b0 = fp0[row0], b1 = fp0[row0+1], b2 = fp0[row0+2], b3 = fp0[row0+3];
        #pragma unroll
        for (int n = 0; n < 4; n++){
          const int col = tn + n*16 + (lane&15);    // token id
          const int bb = col >> 10, nn = col & 1023;
          if (seg < 4){
            u16* dst = (seg < 2) ? Qn : Kn;
            ushort4 pk;
            pk.x = f2bf(acc[m][n][0] + b0);
            pk.y = f2bf(acc[m][n][1] + b1);
            pk.z = f2bf(acc[m][n][2] + b2);
            pk.w = f2bf(acc[m][n][3] + b3);
            *(ushort4*)(dst + ((long long)((bb*2 + hh)*1024 + nn))*DHP + dd0) = pk;
          } else {
            const long long vb = ((long long)(bb*2 + hh)*DHPV + dd0)*1024 + nn;
            Vt[vb        ] = f2bf(acc[m][n][0] + b0);
            Vt[vb + 1024 ] = f2bf(acc[m][n][1] + b1);
            Vt[vb + 2048 ] = f2bf(acc[m][n][2] + b2);
            Vt[vb + 3072 ] = f2bf(acc[m][n][3] + b3);
          }
        }
      }
    }
  } else if constexpr (EPI == 2){
    // P = exp(sim) (|sim|<=~0.1, no max needed) + fused rowsum (atomic per 16-lane group)
    u16* Pb = (u16*)vp1; float* rs = (float*)vp2;
    #pragma unroll
    for (int m = 0; m < 8; m++){
      #pragma unroll
      for (int i = 0; i < 4; i++){
        const int row = tm + m*16 + (lane>>4)*4 + i;
        float s = 0.f;
        #pragma unroll
        for (int n = 0; n < 4; n++){
          const int col = tn + n*16 + (lane&15);
          u16 pb = f2bf(__expf(acc[m][n][i]));
          Pb[(long long)bz*1048576 + (long long)row*1024 + col] = pb;
          s += bf2f(pb);
        }
        s += __shfl_xor(s, 1, 64); s += __shfl_xor(s, 2, 64);
        s += __shfl_xor(s, 4, 64); s += __shfl_xor(s, 8, 64);
        if ((lane & 15) == 0) atomicAdd(rs + bz*1024 + row, s);
      }
    }
  } else {
    #pragma unroll
    for (int m = 0; m < 8; m++){
      #pragma unroll
      for (int n = 0; n < 4; n++){
        #pragma unroll
        for (int i = 0; i < 4; i++){
          const int row = tm + m*16 + (lane>>4)*4 + i;
          const int col = tn + n*16 + (lane&15);
          float v = acc[m][n][i];
          if constexpr (EPI == 3){            // attnout = (P@V)/rowsum, merge heads
            if (col < 392){
              float val = v / fp0[bz*1024 + row];
              int bb = bz >> 1, hh = bz & 1;
              ((u16*)vp1)[((long long)(bb*1024 + row))*784 + hh*392 + col] = f2bf(val);
            }
          } else if constexpr (EPI == 4){     // s = h + hardswish(ffn)
            if (col < KP){
              u16 o = 0;
              if (col < 784){
                float f = v + fp0[col];
                f = f * fminf(fmaxf(f + 3.f, 0.f), 6.f) * (1.f/6.f);
                float hv = bf2f(((const u16*)vp1)[(long long)row*KP + col]);
                o = f2bf(hv + f);
              }
              ((u16*)vp2)[(long long)row*KP + col] = o;
            }
          } else {                            // EPI 5: final fp32 output
            if (col < 784){
              ((float*)vp1)[(long long)row*784 + col] = v + fp0[col];
            }
          }
        }
      }
    }
  }
}

extern "C" void kernel_launch(void* const* d_in, const int* in_sizes, int n_in,
                              void* d_out, int out_size, void* d_ws, size_t ws_size,
                              hipStream_t stream)
{
  const float* x     = (const float*)d_in[0];
  const float* ln_w  = (const float*)d_in[1];
  const float* ln_b  = (const float*)d_in[2];
  const float* qkv_w = (const float*)d_in[3];
  const float* qkv_b = (const float*)d_in[4];
  const float* scale = (const float*)d_in[5];
  const float* out_w = (const float*)d_in[6];
  const float* out_b = (const float*)d_in[7];
  const float* ffn_w = (const float*)d_in[8];
  const float* ffn_b = (const float*)d_in[9];

  char* wsp = (char*)d_ws;
  auto alloc = [&](long long bytes)->char*{ char* p = wsp; wsp += (bytes + 255) & ~255LL; return p; };
  u16* XN   = (u16*)alloc((long long)TOK*KP*2);     // LN1 output (later aliased as attnout)
  u16* WQKV = (u16*)alloc((long long)NQKV*KP*2);    // qkv_w padded [2560, 832]
  u16* WFF  = (u16*)alloc(1024LL*KP*2);             // ffn_w padded [1024, 832]
  u16* WO   = (u16*)alloc(1024LL*KP*2);
  u16* QN   = (u16*)alloc(64LL*1024*DHP*2);         // later aliased as h
  u16* KN   = (u16*)alloc(64LL*1024*DHP*2);         // later aliased as s
  u16* VT   = (u16*)alloc(64LL*DHPV*1024*2);
  u16* P    = (u16*)alloc(64LL*1024*1024*2);
  float* RS = (float*)alloc(65536LL*4);
  u16* ATT = XN;   // alias: XN dead after QKV GEMM
  u16* H   = QN;   // alias: QN dead after P GEMM
  u16* S   = KN;   // alias: KN dead after P GEMM
  (void)ws_size; (void)in_sizes; (void)n_in; (void)out_size;

  // weights -> bf16 padded
  wconv_k<<<dim3(((long long)NQKV*KP + 255)/256), 256, 0, stream>>>(qkv_w, WQKV, 2352, (long long)NQKV*KP);
  wconv_k<<<dim3((1024*KP + 255)/256), 256, 0, stream>>>(ffn_w, WFF, 784, 1024LL*KP);
  wconv_k<<<dim3((1024*KP + 255)/256), 256, 0, stream>>>(out_w, WO,  784, 1024LL*KP);
  vtpad_k<<<dim3((64*120*1024 + 255)/256), 256, 0, stream>>>(VT);
  rszero_k<<<dim3(256), 256, 0, stream>>>(RS);

  // 1) LN1
  ln1_k<<<dim3(TOK), 256, 0, stream>>>(x, ln_w, ln_b, XN);
  // 2) QKV (flipped): [2560,832] @ [32768,832]^T ; ORDER=1: weight tiles cycle fast per XCD chunk
  gemm8_k<0,1><<<dim3(128, 10, 1), 512, 0, stream>>>(WQKV, XN, KP, KP, 26, 0LL, 0LL,
      qkv_b, QN, KN, VT);
  // 3) l2norm q (x sqrt(scale)), k; zero pads
  l2n_k<<<dim3(32768), 256, 0, stream>>>(QN, KN, scale);
  // 4) P = exp(q@k^T) per bh, fused rowsum; ORDER=0: z slow -> 8 bh per XCD, Q/K L2-resident
  gemm8_k<2,0><<<dim3(4, 4, 64), 512, 0, stream>>>(QN, KN, DHP, DHP, 14,
      (long long)1024*DHP, (long long)1024*DHP, nullptr, P, RS, nullptr);
  // 5) attnout = (P @ Vt^T)/rowsum
  gemm8_k<3,0><<<dim3(2, 4, 64), 512, 0, stream>>>(P, VT, 1024, 1024, 32,
      1048576LL, (long long)DHPV*1024, RS, ATT, nullptr, nullptr);
  // 6) LN2 + hardswish -> h
  ln2hs_k<<<dim3(TOK), 256, 0, stream>>>(ATT, ln_w, ln_b, H);
  // 7) s = h + hardswish(h @ ffn_w^T + ffn_b)
  gemm8_k<4,0><<<dim3(4, 128, 1), 512, 0, stream>>>(H, WFF, KP, KP, 26, 0LL, 0LL, ffn_b, H, S, nullptr);
  // 8) y = s @ out_w^T + out_b  (fp32 out)
  gemm8_k<5,0><<<dim3(4, 128, 1), 512, 0, stream>>>(S, WO, KP, KP, 26, 0LL, 0LL, out_b, d_out, nullptr, nullptr);
}